// Round 1
// baseline (955.058 us; speedup 1.0000x reference)
//
#include <hip/hip_runtime.h>
#include <math.h>

#define B_ 16
#define L_ 4096
#define H_ 8
#define E_ 64
#define C_ 512     // H*E
#define K_ 24
#define NT 256

__device__ __forceinline__ int br12(int x) { return (int)(__brev((unsigned)x) >> 20); }

// ---------------- zero scratch ----------------
__global__ __launch_bounds__(256) void k_zero(float* __restrict__ p, int n) {
    int i = blockIdx.x * 256 + threadIdx.x;
    if (i < n) p[i] = 0.f;
}

// ---------------- transpose/pack: (b,tau,c) -> z[bl][c][tau] = (q,k) ----------------
__global__ __launch_bounds__(256) void k_transpose(const float* __restrict__ q,
                                                   const float* __restrict__ k,
                                                   float2* __restrict__ z,
                                                   int b0) {
    __shared__ float tq[64][65];
    __shared__ float tk[64][65];
    int bl = blockIdx.z;
    int b  = b0 + bl;
    int t0 = blockIdx.x * 64;
    int c0 = blockIdx.y * 64;
    int tx = threadIdx.x & 63;
    int ty = threadIdx.x >> 6;
    const size_t base = (size_t)b * L_ * C_;
    for (int rr = ty; rr < 64; rr += 4) {
        size_t off = base + (size_t)(t0 + rr) * C_ + (c0 + tx);
        tq[rr][tx] = q[off];
        tk[rr][tx] = k[off];
    }
    __syncthreads();
    for (int rr = ty; rr < 64; rr += 4) {
        size_t off = ((size_t)bl * C_ + (c0 + rr)) * L_ + (t0 + tx);
        z[off] = make_float2(tq[tx][rr], tk[tx][rr]);
    }
}

// ---------------- forward DIF FFT (packed q+ik) + cross-spectrum accumulate ----------------
__global__ __launch_bounds__(256) void k_fft_accum(const float2* __restrict__ z,
                                                   float* __restrict__ cross, // B*L*2 floats
                                                   int b0) {
    __shared__ float2 s[L_];
    __shared__ float2 tw[L_ / 2];
    int tid = threadIdx.x;
    int bl  = blockIdx.y;
    int b   = b0 + bl;
    int c0  = blockIdx.x * 8;
    for (int j = tid; j < L_ / 2; j += NT) {
        float sn, cs;
        sincospif((float)j / 2048.0f, &sn, &cs);
        tw[j] = make_float2(cs, -sn);       // e^{-2*pi*i*j/4096}
    }
    float accx[16], accy[16];
    #pragma unroll
    for (int r = 0; r < 16; ++r) { accx[r] = 0.f; accy[r] = 0.f; }
    __syncthreads();

    for (int cc = 0; cc < 8; ++cc) {
        const float2* zc = z + ((size_t)bl * C_ + (c0 + cc)) * L_;
        #pragma unroll
        for (int r = 0; r < 16; ++r) s[tid + (r << 8)] = zc[tid + (r << 8)];
        __syncthreads();
        // DIF: natural in -> bit-reversed out
        for (int m = 12; m >= 1; --m) {
            int half = 1 << (m - 1);
            #pragma unroll
            for (int t8 = 0; t8 < 8; ++t8) {
                int t  = tid + (t8 << 8);
                int kk = t & (half - 1);
                int i0 = ((t >> (m - 1)) << m) | kk;
                int i1 = i0 + half;
                float2 a = s[i0], bb = s[i1];
                float2 w = tw[kk << (12 - m)];
                float dx = a.x - bb.x, dy = a.y - bb.y;
                s[i0] = make_float2(a.x + bb.x, a.y + bb.y);
                s[i1] = make_float2(dx * w.x - dy * w.y, dx * w.y + dy * w.x);
            }
            __syncthreads();
        }
        // unpack Z=Q+iK at bit-reversed positions; accumulate C=Q*conj(K)
        #pragma unroll
        for (int r = 0; r < 16; ++r) {
            int p  = tid + (r << 8);
            int f  = br12(p);
            int fn = (L_ - f) & (L_ - 1);
            int pp = br12(fn);
            float2 A = s[p], Bv = s[pp];
            float Qr = 0.5f * (A.x + Bv.x);
            float Qi = 0.5f * (A.y - Bv.y);
            float Kr = 0.5f * (A.y + Bv.y);   // conj(K).x
            float Ki = 0.5f * (A.x - Bv.x);   // conj(K).y
            accx[r] += Qr * Kr - Qi * Ki;
            accy[r] += Qr * Ki + Qi * Kr;
        }
        __syncthreads();
    }
    #pragma unroll
    for (int r = 0; r < 16; ++r) {
        int p = tid + (r << 8);
        atomicAdd(&cross[((size_t)b * L_ + p) * 2 + 0], accx[r]);
        atomicAdd(&cross[((size_t)b * L_ + p) * 2 + 1], accy[r]);
    }
}

// ---------------- inverse DIT FFT (bit-reversed in -> natural out) ----------------
__global__ __launch_bounds__(256) void k_ifft(const float* __restrict__ cross,
                                              float* __restrict__ mv) {
    __shared__ float2 s[L_];
    __shared__ float2 tw[L_ / 2];
    int tid = threadIdx.x;
    int b   = blockIdx.x;
    for (int j = tid; j < L_ / 2; j += NT) {
        float sn, cs;
        sincospif((float)j / 2048.0f, &sn, &cs);
        tw[j] = make_float2(cs, -sn);
    }
    const float2* cr = (const float2*)cross;
    #pragma unroll
    for (int r = 0; r < 16; ++r) {
        int p = tid + (r << 8);
        s[p] = cr[(size_t)b * L_ + p];
    }
    __syncthreads();
    for (int m = 1; m <= 12; ++m) {
        int half = 1 << (m - 1);
        #pragma unroll
        for (int t8 = 0; t8 < 8; ++t8) {
            int t  = tid + (t8 << 8);
            int kk = t & (half - 1);
            int i0 = ((t >> (m - 1)) << m) | kk;
            int i1 = i0 + half;
            float2 a = s[i0], bb = s[i1];
            float2 w = tw[kk << (12 - m)];
            float bwx = bb.x * w.x + bb.y * w.y;   // b * conj(w)  (e^{+i...})
            float bwy = bb.y * w.x - bb.x * w.y;
            s[i0] = make_float2(a.x + bwx, a.y + bwy);
            s[i1] = make_float2(a.x - bwx, a.y - bwy);
        }
        __syncthreads();
    }
    const float scale = 1.0f / ((float)L_ * (float)C_); // irfft 1/N and mean over H*E
    #pragma unroll
    for (int r = 0; r < 16; ++r) {
        int p = tid + (r << 8);
        mv[(size_t)b * L_ + p] = s[p].x * scale;
    }
}

// ---------------- top-24 + per-batch softmax ----------------
__global__ __launch_bounds__(256) void k_topk(const float* __restrict__ mv,
                                              int* __restrict__ idx,
                                              float* __restrict__ wts) {
    __shared__ float sc[L_];
    __shared__ float rv[NT];
    __shared__ int   ri[NT];
    __shared__ int   idxL[K_];
    int tid = threadIdx.x;
    for (int r = 0; r < 16; ++r) {
        int t = tid + (r << 8);
        float ssum = 0.f;
        for (int b = 0; b < B_; ++b) ssum += mv[(size_t)b * L_ + t];
        sc[t] = ssum;
    }
    __syncthreads();
    for (int i = 0; i < K_; ++i) {
        float best = -INFINITY; int bi = L_;
        for (int r = 0; r < 16; ++r) {
            int t = tid + (r << 8);
            float v = sc[t];
            if (v > best || (v == best && t < bi)) { best = v; bi = t; }
        }
        rv[tid] = best; ri[tid] = bi;
        __syncthreads();
        for (int off = 128; off > 0; off >>= 1) {
            if (tid < off) {
                float v2 = rv[tid + off]; int i2 = ri[tid + off];
                if (v2 > rv[tid] || (v2 == rv[tid] && i2 < ri[tid])) { rv[tid] = v2; ri[tid] = i2; }
            }
            __syncthreads();
        }
        if (tid == 0) { idxL[i] = ri[0]; idx[i] = ri[0]; sc[ri[0]] = -INFINITY; }
        __syncthreads();
    }
    if (tid < B_) {
        int b = tid;
        float w[K_]; float wm = -INFINITY;
        for (int i = 0; i < K_; ++i) { w[i] = mv[(size_t)b * L_ + idxL[i]]; wm = fmaxf(wm, w[i]); }
        float ssum = 0.f;
        for (int i = 0; i < K_; ++i) { w[i] = expf(w[i] - wm); ssum += w[i]; }
        float inv = 1.f / ssum;
        for (int i = 0; i < K_; ++i) wts[b * K_ + i] = w[i] * inv;
    }
}

// ---------------- 24-tap circulant gather-sum ----------------
__global__ __launch_bounds__(256) void k_agg(const float* __restrict__ vals,
                                             const int* __restrict__ idx,
                                             const float* __restrict__ wts,
                                             float* __restrict__ out) {
    __shared__ int   di[K_];
    __shared__ float dw[K_];
    int tid = threadIdx.x;
    int tau = blockIdx.x;
    int b   = blockIdx.y;
    if (tid < K_) { di[tid] = idx[tid]; dw[tid] = wts[b * K_ + tid]; }
    __syncthreads();
    float2 acc = make_float2(0.f, 0.f);
    const float2* v2 = (const float2*)vals;
    for (int i = 0; i < K_; ++i) {
        int row = (tau + di[i]) & (L_ - 1);
        float2 x = v2[((size_t)b * L_ + row) * (C_ / 2) + tid];
        acc.x += dw[i] * x.x;
        acc.y += dw[i] * x.y;
    }
    ((float2*)out)[((size_t)b * L_ + tau) * (C_ / 2) + tid] = acc;
}

extern "C" void kernel_launch(void* const* d_in, const int* in_sizes, int n_in,
                              void* d_out, int out_size, void* d_ws, size_t ws_size,
                              hipStream_t stream) {
    const float* q = (const float*)d_in[0];
    const float* k = (const float*)d_in[1];
    const float* v = (const float*)d_in[2];
    float* out = (float*)d_out;
    char* ws = (char*)d_ws;

    // ws layout: [cross 512KB | mv 256KB | idx | wts | ... | z at 2MB]
    float* cross = (float*)ws;
    float* mv    = (float*)(ws + (1 << 20));
    int*   idx   = (int*)(ws + (1 << 20) + (1 << 18));
    float* wts   = (float*)(ws + (1 << 20) + (1 << 18) + 4096);
    float2* z    = (float2*)(ws + (2 << 20));

    size_t zcap = (ws_size > (size_t)(2 << 20)) ? ws_size - (size_t)(2 << 20) : 0;
    int P = 16;
    while (P > 1 && (size_t)P * C_ * L_ * sizeof(float2) > zcap) P >>= 1;

    k_zero<<<(B_ * L_ * 2 + 255) / 256, 256, 0, stream>>>(cross, B_ * L_ * 2);

    for (int b0 = 0; b0 < B_; b0 += P) {
        dim3 gt(L_ / 64, C_ / 64, P);
        k_transpose<<<gt, 256, 0, stream>>>(q, k, z, b0);
        dim3 gf(C_ / 8, P);
        k_fft_accum<<<gf, 256, 0, stream>>>(z, cross, b0);
    }
    k_ifft<<<B_, 256, 0, stream>>>(cross, mv);
    k_topk<<<1, 256, 0, stream>>>(mv, idx, wts);
    dim3 ga(L_, B_);
    k_agg<<<ga, 256, 0, stream>>>(v, idx, wts, out);
}

// Round 2
// 787.428 us; speedup vs baseline: 1.2129x; 1.2129x over previous
//
#include <hip/hip_runtime.h>
#include <math.h>

#define B_ 16
#define L_ 4096
#define H_ 8
#define E_ 64
#define C_ 512     // H*E
#define K_ 24
#define NT 256
#define RPAD 257   // padded row stride (float2 units) for the 16x256 LDS matrix

__device__ __forceinline__ int br12(int x) { return (int)(__brev((unsigned)x) >> 20); }

__device__ __forceinline__ float2 cmul(float2 a, float2 b) {
    return make_float2(a.x * b.x - a.y * b.y, a.x * b.y + a.y * b.x);
}
__device__ __forceinline__ float2 cadd(float2 a, float2 b) { return make_float2(a.x + b.x, a.y + b.y); }
__device__ __forceinline__ float2 csub(float2 a, float2 b) { return make_float2(a.x - b.x, a.y - b.y); }

// 16-point DIF FFT, natural-order input; output: X[k] = a[br4[k]]
__device__ __forceinline__ void fft16(float2 a[16]) {
    const float r2 = 0.70710678118654752f;
    const float c1 = 0.92387953251128676f;  // cos(pi/8)
    const float s1 = 0.38268343236508977f;  // sin(pi/8)
    const float2 W16[8] = {
        make_float2(1.f, 0.f),  make_float2(c1, -s1),  make_float2(r2, -r2),  make_float2(s1, -c1),
        make_float2(0.f, -1.f), make_float2(-s1, -c1), make_float2(-r2, -r2), make_float2(-c1, -s1)};
    #pragma unroll
    for (int j = 0; j < 8; ++j) {
        float2 u = a[j], v = a[j + 8];
        a[j]     = cadd(u, v);
        a[j + 8] = cmul(csub(u, v), W16[j]);
    }
    #pragma unroll
    for (int b = 0; b < 16; b += 8)
        #pragma unroll
        for (int j = 0; j < 4; ++j) {
            float2 u = a[b + j], v = a[b + j + 4];
            a[b + j]     = cadd(u, v);
            a[b + j + 4] = cmul(csub(u, v), W16[2 * j]);
        }
    #pragma unroll
    for (int b = 0; b < 16; b += 4)
        #pragma unroll
        for (int j = 0; j < 2; ++j) {
            float2 u = a[b + j], v = a[b + j + 2];
            a[b + j]     = cadd(u, v);
            a[b + j + 2] = cmul(csub(u, v), W16[4 * j]);
        }
    #pragma unroll
    for (int b = 0; b < 16; b += 2) {
        float2 u = a[b], v = a[b + 1];
        a[b]     = cadd(u, v);
        a[b + 1] = csub(u, v);
    }
}

// ---------------- zero scratch ----------------
__global__ __launch_bounds__(256) void k_zero(float* __restrict__ p, int n) {
    int i = blockIdx.x * 256 + threadIdx.x;
    if (i < n) p[i] = 0.f;
}

// ---------------- transpose/pack: (b,tau,c) -> z[bl][c][tau] = (q,k) ----------------
__global__ __launch_bounds__(256) void k_transpose(const float* __restrict__ q,
                                                   const float* __restrict__ k,
                                                   float2* __restrict__ z,
                                                   int b0) {
    __shared__ float tq[64][65];
    __shared__ float tk[64][65];
    int bl = blockIdx.z;
    int b  = b0 + bl;
    int t0 = blockIdx.x * 64;
    int c0 = blockIdx.y * 64;
    int tx = threadIdx.x & 63;
    int ty = threadIdx.x >> 6;
    const size_t base = (size_t)b * L_ * C_;
    for (int rr = ty; rr < 64; rr += 4) {
        size_t off = base + (size_t)(t0 + rr) * C_ + (c0 + tx);
        tq[rr][tx] = q[off];
        tk[rr][tx] = k[off];
    }
    __syncthreads();
    for (int rr = ty; rr < 64; rr += 4) {
        size_t off = ((size_t)bl * C_ + (c0 + rr)) * L_ + (t0 + tx);
        z[off] = make_float2(tq[tx][rr], tk[tx][rr]);
    }
}

// ---------------- forward FFT (register radix-16, 3 phases) + cross-spectrum ----------------
// Decomposition: n = n1*256 + n2; k = r2*256 + r1*16 + k1.
// Phase A: 16-pt DFT over n1 (thread t = n2), twiddle W4096^{n2*k1}, store [k1][n2].
// Phase B: per row k1, 16-pt DFT over m1 (n2 = m1*16+m2), twiddle W256^{m2*r1}, store [k1][r1*16+m2].
// Phase C: 16-pt DFT over m2, natural-order store X[256*r2+16*r1+k1].
__global__ __launch_bounds__(256) void k_fft_accum(const float2* __restrict__ z,
                                                   float* __restrict__ cross, // B*L*2 floats
                                                   int b0) {
    __shared__ float2 s[16 * RPAD];   // 4112 float2 = 32.9 KB
    __shared__ float2 tw256[256];     // tw256[r1*16+m2] = W256^{m2*r1}
    const int br4[16] = {0, 8, 4, 12, 2, 10, 6, 14, 1, 9, 5, 13, 3, 11, 7, 15};
    int t  = threadIdx.x;
    int bl = blockIdx.y;
    int b  = b0 + bl;
    int c0 = blockIdx.x * 8;

    {
        int r1 = t >> 4, m2 = t & 15;
        float sn, cs;
        sincospif((float)(r1 * m2) / 128.0f, &sn, &cs);
        tw256[t] = make_float2(cs, -sn);
    }
    // phase-A twiddles W4096^{t*k1} (channel-invariant)
    float2 twA[15];
    #pragma unroll
    for (int k1 = 1; k1 < 16; ++k1) {
        float sn, cs;
        sincospif((float)(t * k1) / 2048.0f, &sn, &cs);
        twA[k1 - 1] = make_float2(cs, -sn);
    }
    float accx[16], accy[16];
    #pragma unroll
    for (int r = 0; r < 16; ++r) { accx[r] = 0.f; accy[r] = 0.f; }
    __syncthreads();

    const int rowB = t >> 4, m2B = t & 15;
    const int k1C = t & 15, r1C = t >> 4;

    for (int cc = 0; cc < 8; ++cc) {
        const float2* zc = z + ((size_t)bl * C_ + (c0 + cc)) * L_;
        float2 a[16];
        // ---- phase A ----
        #pragma unroll
        for (int n1 = 0; n1 < 16; ++n1) a[n1] = zc[(n1 << 8) + t];
        fft16(a);
        #pragma unroll
        for (int k1 = 0; k1 < 16; ++k1) {
            float2 v = a[br4[k1]];
            if (k1) v = cmul(v, twA[k1 - 1]);
            s[k1 * RPAD + t] = v;
        }
        __syncthreads();
        // ---- phase B ----
        #pragma unroll
        for (int m1 = 0; m1 < 16; ++m1) a[m1] = s[rowB * RPAD + (m1 << 4) + m2B];
        fft16(a);
        __syncthreads();
        #pragma unroll
        for (int r1 = 0; r1 < 16; ++r1) {
            float2 v = cmul(a[br4[r1]], tw256[(r1 << 4) + m2B]);
            s[rowB * RPAD + (r1 << 4) + m2B] = v;
        }
        __syncthreads();
        // ---- phase C ----
        #pragma unroll
        for (int m2 = 0; m2 < 16; ++m2) a[m2] = s[k1C * RPAD + (r1C << 4) + m2];
        fft16(a);
        __syncthreads();
        #pragma unroll
        for (int r2 = 0; r2 < 16; ++r2)
            s[(r2 << 8) + (r1C << 4) + k1C] = a[br4[r2]];   // natural order, flat
        __syncthreads();
        // ---- unpack Z=Q+iK, accumulate Q*conj(K) (natural bin order) ----
        #pragma unroll
        for (int r = 0; r < 16; ++r) {
            int p  = t + (r << 8);
            int pp = (L_ - p) & (L_ - 1);
            float2 A  = s[p];
            float2 Bv = s[pp];
            float Qr = 0.5f * (A.x + Bv.x);
            float Qi = 0.5f * (A.y - Bv.y);
            float Kr = 0.5f * (A.y + Bv.y);
            float Ki = 0.5f * (A.x - Bv.x);
            accx[r] += Qr * Kr - Qi * Ki;
            accy[r] += Qr * Ki + Qi * Kr;
        }
        __syncthreads();
    }
    #pragma unroll
    for (int r = 0; r < 16; ++r) {
        int p = t + (r << 8);
        atomicAdd(&cross[((size_t)b * L_ + p) * 2 + 0], accx[r]);
        atomicAdd(&cross[((size_t)b * L_ + p) * 2 + 1], accy[r]);
    }
}

// ---------------- inverse DIT FFT (natural-order cross input via bit-rev gather) ----------------
__global__ __launch_bounds__(256) void k_ifft(const float* __restrict__ cross,
                                              float* __restrict__ mv) {
    __shared__ float2 s[L_];
    __shared__ float2 tw[L_ / 2];
    int tid = threadIdx.x;
    int b   = blockIdx.x;
    for (int j = tid; j < L_ / 2; j += NT) {
        float sn, cs;
        sincospif((float)j / 2048.0f, &sn, &cs);
        tw[j] = make_float2(cs, -sn);
    }
    const float2* cr = (const float2*)cross;
    #pragma unroll
    for (int r = 0; r < 16; ++r) {
        int p = tid + (r << 8);
        s[p] = cr[(size_t)b * L_ + br12(p)];
    }
    __syncthreads();
    for (int m = 1; m <= 12; ++m) {
        int half = 1 << (m - 1);
        #pragma unroll
        for (int t8 = 0; t8 < 8; ++t8) {
            int t  = tid + (t8 << 8);
            int kk = t & (half - 1);
            int i0 = ((t >> (m - 1)) << m) | kk;
            int i1 = i0 + half;
            float2 a = s[i0], bb = s[i1];
            float2 w = tw[kk << (12 - m)];
            float bwx = bb.x * w.x + bb.y * w.y;   // b * conj(w)
            float bwy = bb.y * w.x - bb.x * w.y;
            s[i0] = make_float2(a.x + bwx, a.y + bwy);
            s[i1] = make_float2(a.x - bwx, a.y - bwy);
        }
        __syncthreads();
    }
    const float scale = 1.0f / ((float)L_ * (float)C_);
    #pragma unroll
    for (int r = 0; r < 16; ++r) {
        int p = tid + (r << 8);
        mv[(size_t)b * L_ + p] = s[p].x * scale;
    }
}

// ---------------- top-24 + per-batch softmax ----------------
__global__ __launch_bounds__(256) void k_topk(const float* __restrict__ mv,
                                              int* __restrict__ idx,
                                              float* __restrict__ wts) {
    __shared__ float sc[L_];
    __shared__ float rv[NT];
    __shared__ int   ri[NT];
    __shared__ int   idxL[K_];
    int tid = threadIdx.x;
    for (int r = 0; r < 16; ++r) {
        int t = tid + (r << 8);
        float ssum = 0.f;
        for (int b = 0; b < B_; ++b) ssum += mv[(size_t)b * L_ + t];
        sc[t] = ssum;
    }
    __syncthreads();
    for (int i = 0; i < K_; ++i) {
        float best = -INFINITY; int bi = L_;
        for (int r = 0; r < 16; ++r) {
            int t = tid + (r << 8);
            float v = sc[t];
            if (v > best || (v == best && t < bi)) { best = v; bi = t; }
        }
        rv[tid] = best; ri[tid] = bi;
        __syncthreads();
        for (int off = 128; off > 0; off >>= 1) {
            if (tid < off) {
                float v2 = rv[tid + off]; int i2 = ri[tid + off];
                if (v2 > rv[tid] || (v2 == rv[tid] && i2 < ri[tid])) { rv[tid] = v2; ri[tid] = i2; }
            }
            __syncthreads();
        }
        if (tid == 0) { idxL[i] = ri[0]; idx[i] = ri[0]; sc[ri[0]] = -INFINITY; }
        __syncthreads();
    }
    if (tid < B_) {
        int b = tid;
        float w[K_]; float wm = -INFINITY;
        for (int i = 0; i < K_; ++i) { w[i] = mv[(size_t)b * L_ + idxL[i]]; wm = fmaxf(wm, w[i]); }
        float ssum = 0.f;
        for (int i = 0; i < K_; ++i) { w[i] = expf(w[i] - wm); ssum += w[i]; }
        float inv = 1.f / ssum;
        for (int i = 0; i < K_; ++i) wts[b * K_ + i] = w[i] * inv;
    }
}

// ---------------- 24-tap circulant gather-sum ----------------
__global__ __launch_bounds__(256) void k_agg(const float* __restrict__ vals,
                                             const int* __restrict__ idx,
                                             const float* __restrict__ wts,
                                             float* __restrict__ out) {
    __shared__ int   di[K_];
    __shared__ float dw[K_];
    int tid = threadIdx.x;
    int tau = blockIdx.x;
    int b   = blockIdx.y;
    if (tid < K_) { di[tid] = idx[tid]; dw[tid] = wts[b * K_ + tid]; }
    __syncthreads();
    float2 acc = make_float2(0.f, 0.f);
    const float2* v2 = (const float2*)vals;
    for (int i = 0; i < K_; ++i) {
        int row = (tau + di[i]) & (L_ - 1);
        float2 x = v2[((size_t)b * L_ + row) * (C_ / 2) + tid];
        acc.x += dw[i] * x.x;
        acc.y += dw[i] * x.y;
    }
    ((float2*)out)[((size_t)b * L_ + tau) * (C_ / 2) + tid] = acc;
}

extern "C" void kernel_launch(void* const* d_in, const int* in_sizes, int n_in,
                              void* d_out, int out_size, void* d_ws, size_t ws_size,
                              hipStream_t stream) {
    const float* q = (const float*)d_in[0];
    const float* k = (const float*)d_in[1];
    const float* v = (const float*)d_in[2];
    float* out = (float*)d_out;
    char* ws = (char*)d_ws;

    // ws layout: [cross 512KB | mv 256KB | idx | wts | ... | z at 2MB]
    float* cross = (float*)ws;
    float* mv    = (float*)(ws + (1 << 20));
    int*   idx   = (int*)(ws + (1 << 20) + (1 << 18));
    float* wts   = (float*)(ws + (1 << 20) + (1 << 18) + 4096);
    float2* z    = (float2*)(ws + (2 << 20));

    size_t zcap = (ws_size > (size_t)(2 << 20)) ? ws_size - (size_t)(2 << 20) : 0;
    int P = 16;
    while (P > 1 && (size_t)P * C_ * L_ * sizeof(float2) > zcap) P >>= 1;

    k_zero<<<(B_ * L_ * 2 + 255) / 256, 256, 0, stream>>>(cross, B_ * L_ * 2);

    for (int b0 = 0; b0 < B_; b0 += P) {
        dim3 gt(L_ / 64, C_ / 64, P);
        k_transpose<<<gt, 256, 0, stream>>>(q, k, z, b0);
        dim3 gf(C_ / 8, P);
        k_fft_accum<<<gf, 256, 0, stream>>>(z, cross, b0);
    }
    k_ifft<<<B_, 256, 0, stream>>>(cross, mv);
    k_topk<<<1, 256, 0, stream>>>(mv, idx, wts);
    dim3 ga(L_, B_);
    k_agg<<<ga, 256, 0, stream>>>(v, idx, wts, out);
}